// Round 1
// baseline (503.322 us; speedup 1.0000x reference)
//
#include <hip/hip_runtime.h>
#include <hip/hip_bf16.h>

// Depthwise 3x3 conv, filter indexed by b only:
// out[b,c,h,w] = sum_{kh,kw} x[b,c,h+kh-1,w+kw-1] * kernel[b,kh,kw]
// x: (16,64,256,256) fp32, kernel: (16,3,3) fp32, out: (16,64,256,256) fp32.
// Memory-bound: ~537 MB HBM traffic, roofline ~85 us @ 6.3 TB/s.

#define BB 16
#define CC 64
#define HH 256
#define WW 256

__global__ __launch_bounds__(256) void ParConv2d_dw3x3(
    const float* __restrict__ x,
    const float* __restrict__ kern,
    float* __restrict__ out)
{
    // Each thread produces 4 consecutive outputs along W.
    // idx = ((b*C + c)*H + h)*(W/4) + w4   -> b is uniform within a block
    // (block covers 256 threads = 64 w4-groups x 4 h values, fixed b,c).
    const int idx = blockIdx.x * 256 + threadIdx.x;
    const int w4 = idx & 63;            // W/4 = 64
    const int h  = (idx >> 6) & 255;    // H = 256
    const int bc = idx >> 14;           // b*C + c
    const int b  = bc >> 6;             // C = 64

    // 9 filter taps: b is wave-uniform -> scalar loads
    const float* kb = kern + b * 9;
    const float k00 = kb[0], k01 = kb[1], k02 = kb[2];
    const float k10 = kb[3], k11 = kb[4], k12 = kb[5];
    const float k20 = kb[6], k21 = kb[7], k22 = kb[8];

    const float* xp = x + (size_t)bc * (HH * WW);
    const int w0 = w4 << 2;

    // row[r][j] holds x[h+r-1][w0-1+j], j in 0..5 (6 cols), zero-padded.
    float row[3][6];
#pragma unroll
    for (int r = 0; r < 3; ++r) {
        const int hh = h + r - 1;
        if (hh < 0 || hh >= HH) {
#pragma unroll
            for (int j = 0; j < 6; ++j) row[r][j] = 0.0f;
        } else {
            const float* rp = xp + hh * WW + w0;
            const float4 v = *(const float4*)rp;   // aligned: w0 % 4 == 0
            row[r][1] = v.x; row[r][2] = v.y; row[r][3] = v.z; row[r][4] = v.w;
            row[r][0] = (w0 > 0)        ? rp[-1] : 0.0f;
            row[r][5] = (w0 + 4 < WW)   ? rp[4]  : 0.0f;
        }
    }

    float res[4];
#pragma unroll
    for (int j = 0; j < 4; ++j) {
        res[j] = k00 * row[0][j] + k01 * row[0][j + 1] + k02 * row[0][j + 2]
               + k10 * row[1][j] + k11 * row[1][j + 1] + k12 * row[1][j + 2]
               + k20 * row[2][j] + k21 * row[2][j + 1] + k22 * row[2][j + 2];
    }

    float4* op = (float4*)(out + (size_t)idx * 4);
    *op = make_float4(res[0], res[1], res[2], res[3]);
}

extern "C" void kernel_launch(void* const* d_in, const int* in_sizes, int n_in,
                              void* d_out, int out_size, void* d_ws, size_t ws_size,
                              hipStream_t stream) {
    const float* x    = (const float*)d_in[0];
    const float* kern = (const float*)d_in[1];
    float* out        = (float*)d_out;

    // total outputs = 16*64*256*256 = 67,108,864; 4 per thread -> 16,777,216 threads
    const int total_threads = BB * CC * HH * (WW / 4);
    const int blocks = total_threads / 256;   // 65536
    ParConv2d_dw3x3<<<blocks, 256, 0, stream>>>(x, kern, out);
}

// Round 2
// 430.058 us; speedup vs baseline: 1.1704x; 1.1704x over previous
//
#include <hip/hip_runtime.h>
#include <hip/hip_bf16.h>

// Depthwise 3x3 conv, filter indexed by b only:
// out[b,c,h,w] = sum_{kh,kw} x[b,c,h+kh-1,w+kw-1] * kernel[b,kh,kw]
// x: (16,64,256,256) fp32, kernel: (16,3,3) fp32, out: same as x.
//
// R1: 10 VMEM/quad, latency-bound at 2.25 TB/s (36% achievable).
// R2: halo via __shfl (lane==w4 spans full W row), 4x h-blocking:
//     6 dwordx4 loads + 4 dwordx4 stores per 16 outputs.

#define CC 64
#define HH 256
#define WW 256

__global__ __launch_bounds__(256) void ParConv2d_dw3x3(
    const float* __restrict__ x,
    const float* __restrict__ kern,
    float* __restrict__ out)
{
    const int tid  = threadIdx.x;
    const int lane = tid & 63;      // lane == w4; 64 lanes * 4 floats = full W row
    const int wave = tid >> 6;      // 4 waves per block
    const int tile = blockIdx.x & 15;   // 16 h-tiles of 16 rows each
    const int bc   = blockIdx.x >> 4;   // b*C + c
    const int b    = bc >> 6;           // C = 64

    // 9 filter taps: b is block-uniform -> scalar loads
    const float* kb = kern + b * 9;
    const float k00 = kb[0], k01 = kb[1], k02 = kb[2];
    const float k10 = kb[3], k11 = kb[4], k12 = kb[5];
    const float k20 = kb[6], k21 = kb[7], k22 = kb[8];

    const float* xp = x + (size_t)bc * (HH * WW);
    const int h0 = tile * 16 + wave * 4;   // first output row of this thread
    const int w0 = lane << 2;

    // win[r][j] = x[h0+r-1][w0-1+j], r in 0..5, j in 0..5, zero-padded.
    float win[6][6];
#pragma unroll
    for (int r = 0; r < 6; ++r) {
        const int hh = h0 + r - 1;
        float4 v = make_float4(0.f, 0.f, 0.f, 0.f);
        if (hh >= 0 && hh < HH) {          // wave-uniform branch
            v = *(const float4*)(xp + hh * WW + w0);
        }
        const float l = __shfl_up(v.w, 1);     // lane-1's last element
        const float rr = __shfl_down(v.x, 1);  // lane+1's first element
        win[r][0] = (lane == 0)  ? 0.f : l;
        win[r][1] = v.x; win[r][2] = v.y; win[r][3] = v.z; win[r][4] = v.w;
        win[r][5] = (lane == 63) ? 0.f : rr;
    }

    float* op = out + (size_t)bc * (HH * WW) + (size_t)h0 * WW + w0;
#pragma unroll
    for (int orow = 0; orow < 4; ++orow) {
        float res[4];
#pragma unroll
        for (int j = 0; j < 4; ++j) {
            res[j] = k00 * win[orow][j]     + k01 * win[orow][j + 1]     + k02 * win[orow][j + 2]
                   + k10 * win[orow + 1][j] + k11 * win[orow + 1][j + 1] + k12 * win[orow + 1][j + 2]
                   + k20 * win[orow + 2][j] + k21 * win[orow + 2][j + 1] + k22 * win[orow + 2][j + 2];
        }
        *(float4*)(op + orow * WW) = make_float4(res[0], res[1], res[2], res[3]);
    }
}

extern "C" void kernel_launch(void* const* d_in, const int* in_sizes, int n_in,
                              void* d_out, int out_size, void* d_ws, size_t ws_size,
                              hipStream_t stream) {
    const float* x    = (const float*)d_in[0];
    const float* kern = (const float*)d_in[1];
    float* out        = (float*)d_out;

    // grid: (b*C) images x 16 h-tiles; block: 4 waves x 64 lanes
    const int blocks = 16 * CC * 16;   // 16384
    ParConv2d_dw3x3<<<blocks, 256, 0, stream>>>(x, kern, out);
}